// Round 7
// baseline (58.214 us; speedup 1.0000x reference)
//
#include <hip/hip_runtime.h>
#include <math.h>

// Fuzzyfier: out[b,v,s,p] = mv >= 0.1 ? mv : 0,  mv = exp(-(x-c)^2 / (2 s^2))
// x (64,8,1024) f32, fuzzy_sets (8,64,2) f32 [c, sigma]. Out 134 MB f32.
// Measured pure-write ceiling (harness fillBuffer): 6.56-6.91 TB/s -> ~20 us.
// R5 = 27.7 us (4.85 TB/s, 72%): VALU/issue-bound, not write-bound.
//
// R6b: 8 p-values per thread per iter (2x 16B nontemporal stores, 32 B/lane)
//   - halves x-loads + loop overhead per byte, 8 independent exp2 chains
//   - nt stores: output is write-once, skip L2 write-allocate churn
//   - store via native ext_vector_type(4) (HIP_vector_type rejected by the
//     nontemporal builtin - R6 compile fail)
// Fast path per element: sub, mul, mul, v_exp_f32, cmp, sel (+2-op band check).
// Alpha-cut decisions protected by the R4/R5-proven rare f64 band recompute
// (|u - log2 0.1| < 2e-3; fast-path decision error ~3e-7 << band).

#define LOG2E    1.4426950408889634f
#define LOG2_CUT -3.321928094887362f   // log2(0.1)
#define BAND2    2e-3f

typedef float f32x4 __attribute__((ext_vector_type(4)));

#if __has_builtin(__builtin_amdgcn_exp2f)
#define FAST_EXP2(x) __builtin_amdgcn_exp2f(x)
#else
#define FAST_EXP2(x) exp2f(x)
#endif

__global__ __launch_bounds__(256) void fuzzyfier_kernel(
    const float* __restrict__ x,     // B*V*S
    const float* __restrict__ fs,    // V*P*2 interleaved (c, sigma)
    float* __restrict__ out,         // B*V*S*P
    int total8)                      // (B*V*S*P)/8
{
    int idx    = blockIdx.x * 256 + threadIdx.x;
    int stride = gridDim.x * 256;    // 524288; row-delta 65536 -> v invariant

    // Per-thread invariants: 8 consecutive p starting at q, variable v.
    int q  = (idx & 7) << 3;               // p base 0,8,...,56
    int v  = ((idx >> 3) >> 10) & 7;       // S = 1024
    int pb = (v << 6) + q;

    float c[8], w[8], sg[8];
    #pragma unroll
    for (int k = 0; k < 8; ++k) {
        float2 cs = reinterpret_cast<const float2*>(fs)[pb + k];  // 4 KB, hot
        c[k]  = cs.x;
        sg[k] = cs.y;
        w[k]  = -LOG2E / (2.0f * (cs.y * cs.y));   // one-time precise div
    }

    for (int i = idx; i < total8; i += stride) {
        int row  = i >> 3;
        float xv = x[row];               // 8 lanes share -> L1 broadcast

        float o[8];
        #pragma unroll
        for (int k = 0; k < 8; ++k) {
            float d = xv - c[k];
            float u = (d * d) * w[k];            // = log2(mv), ~2 ulp
            float m = FAST_EXP2(u);              // v_exp_f32 (trans pipe)
            o[k] = (m >= 0.1f) ? m : 0.0f;
            if (__builtin_expect(fabsf(u - LOG2_CUT) < BAND2, 0)) {
                // boundary band: replicate numpy's float64 pipeline exactly
                double dd = (double)xv - (double)c[k];
                double sd = (double)sg[k];
                double td = -(dd * dd) / (2.0 * (sd * sd));
                double md = exp(td);
                o[k] = (md >= 0.1) ? (float)md : 0.0f;
            }
        }

        // 32 B/lane: wave writes 2 KiB contiguous, nontemporal (write-once)
        f32x4* o4 = reinterpret_cast<f32x4*>(out);
        f32x4 lo = { o[0], o[1], o[2], o[3] };
        f32x4 hi = { o[4], o[5], o[6], o[7] };
        __builtin_nontemporal_store(lo, &o4[2 * i]);
        __builtin_nontemporal_store(hi, &o4[2 * i + 1]);
    }
}

extern "C" void kernel_launch(void* const* d_in, const int* in_sizes, int n_in,
                              void* d_out, int out_size, void* d_ws, size_t ws_size,
                              hipStream_t stream) {
    const float* x  = (const float*)d_in[0];
    const float* fs = (const float*)d_in[1];
    float* out      = (float*)d_out;

    int total8 = out_size / 8;   // 4,194,304 8-element chunks

    const int block = 256;
    const int grid  = 2048;      // keep ==0 mod 512 for (v,q) invariance

    hipLaunchKernelGGL(fuzzyfier_kernel, dim3(grid), dim3(block), 0, stream,
                       x, fs, out, total8);
}

// Round 8
// 27.804 us; speedup vs baseline: 2.0937x; 2.0937x over previous
//
#include <hip/hip_runtime.h>
#include <math.h>

// Fuzzyfier: out[b,v,s,p] = mv >= 0.1 ? mv : 0,  mv = exp(-(x-c)^2 / (2 s^2))
// x (64,8,1024) f32, fuzzy_sets (8,64,2) f32 [c, sigma]. Out 134 MB f32.
// Measured pure-write ceiling (harness fillBuffer): 6.6-6.9 TB/s -> ~20 us.
//
// R5 = 27.7 us (4.85 TB/s) with lane->(row, 4p) mapping, 16 B/lane stores.
// R7 REGRESSED (58 us): 8p/thread made each store instr 16B@32B-stride
// (holes per instruction) + nt partial-line WC -> ~2x write cost. Lesson:
// per-INSTRUCTION contiguity is what matters, not per-wave coverage.
//
// R8: keep R5's mapping (lane i -> q=(i&15)*4, each store instr = 1 KiB
// solid per wave), but process TWO rows (rowA, rowA+4) per thread per iter:
// same (v,q) -> same 4 (c,w,sg) regs, 2 x-loads, 8 elems, 2 contiguous
// stores. Regular cached stores (no nt). Halves loop overhead per byte,
// doubles exp2 ILP.
//
// Alpha-cut decisions protected by the R4/R5-proven rare f64 band recompute
// (|u - log2 0.1| < 2e-3; fast-path decision error ~3e-7 << band width).

#define LOG2E    1.4426950408889634f
#define LOG2_CUT -3.321928094887362f   // log2(0.1)
#define BAND2    2e-3f

#if __has_builtin(__builtin_amdgcn_exp2f)
#define FAST_EXP2(x) __builtin_amdgcn_exp2f(x)
#else
#define FAST_EXP2(x) exp2f(x)
#endif

__global__ __launch_bounds__(256) void fuzzyfier_kernel(
    const float* __restrict__ x,     // B*V*S
    const float* __restrict__ fs,    // V*P*2 interleaved (c, sigma)
    float* __restrict__ out,         // B*V*S*P
    int totalPair)                   // (B*V*S*P)/8 row-pair chunks
{
    int idx    = blockIdx.x * 256 + threadIdx.x;
    int stride = gridDim.x * 256;    // 524288 -> (v,q) invariant per thread

    // i = 16*jj + q ; rowA = 8*(jj>>2) + (jj&3) ; rowB = rowA + 4.
    // Wave (64 lanes, aligned): jj spans 4 consecutive -> store A covers
    // rows 8J..8J+3 x 16 chunks = 1 KiB solid; store B rows 8J+4..8J+7.
    int q4 = (idx & 15) << 2;                    // p base (invariant)
    int j0 = idx >> 4;
    int rA0 = ((j0 >> 2) << 3) + (j0 & 3);
    int v   = (rA0 >> 10) & 7;                   // invariant (stride -> +64 v-units)
    int pb  = (v << 6) + q4;

    float c[4], w[4], sg[4];
    #pragma unroll
    for (int k = 0; k < 4; ++k) {
        float2 cs = reinterpret_cast<const float2*>(fs)[pb + k];  // 4 KB, hot
        c[k]  = cs.x;
        sg[k] = cs.y;
        w[k]  = -LOG2E / (2.0f * (cs.y * cs.y));   // one-time precise div
    }

    float4* o4 = reinterpret_cast<float4*>(out);

    for (int i = idx; i < totalPair; i += stride) {
        int jj   = i >> 4;
        int q    = i & 15;
        int rowA = ((jj >> 2) << 3) + (jj & 3);
        int rowB = rowA + 4;                 // same v (8-row block, 8 | 1024)
        float xa = x[rowA];                  // 16 lanes share -> L1 broadcast
        float xb = x[rowB];

        float oa[4], ob[4];
        #pragma unroll
        for (int k = 0; k < 4; ++k) {
            float da = xa - c[k];
            float ua = (da * da) * w[k];         // = log2(mv)
            float ma = FAST_EXP2(ua);
            oa[k] = (ma >= 0.1f) ? ma : 0.0f;
            if (__builtin_expect(fabsf(ua - LOG2_CUT) < BAND2, 0)) {
                double dd = (double)xa - (double)c[k];
                double sd = (double)sg[k];
                double md = exp(-(dd * dd) / (2.0 * (sd * sd)));
                oa[k] = (md >= 0.1) ? (float)md : 0.0f;
            }
            float db = xb - c[k];
            float ub = (db * db) * w[k];
            float mb = FAST_EXP2(ub);
            ob[k] = (mb >= 0.1f) ? mb : 0.0f;
            if (__builtin_expect(fabsf(ub - LOG2_CUT) < BAND2, 0)) {
                double dd = (double)xb - (double)c[k];
                double sd = (double)sg[k];
                double md = exp(-(dd * dd) / (2.0 * (sd * sd)));
                ob[k] = (md >= 0.1) ? (float)md : 0.0f;
            }
        }

        // Each store instruction: wave writes 1 KiB contiguous.
        o4[rowA * 16 + q] = make_float4(oa[0], oa[1], oa[2], oa[3]);
        o4[rowB * 16 + q] = make_float4(ob[0], ob[1], ob[2], ob[3]);
    }
}

extern "C" void kernel_launch(void* const* d_in, const int* in_sizes, int n_in,
                              void* d_out, int out_size, void* d_ws, size_t ws_size,
                              hipStream_t stream) {
    const float* x  = (const float*)d_in[0];
    const float* fs = (const float*)d_in[1];
    float* out      = (float*)d_out;

    int totalPair = out_size / 8;   // 4,194,304 (exactly 8 iters/thread)

    const int block = 256;
    const int grid  = 2048;         // keep ==0 mod 512 for (v,q) invariance

    hipLaunchKernelGGL(fuzzyfier_kernel, dim3(grid), dim3(block), 0, stream,
                       x, fs, out, totalPair);
}

// Round 9
// 27.621 us; speedup vs baseline: 2.1076x; 1.0066x over previous
//
#include <hip/hip_runtime.h>
#include <math.h>

// Fuzzyfier: out[b,v,s,p] = mv >= 0.1 ? mv : 0,  mv = exp(-(x-c)^2 / (2 s^2))
// x (64,8,1024) f32, fuzzy_sets (8,64,2) f32 [c, sigma]. Out 134 MB f32.
// Write ceiling (measured fillBuffer): 6.6-6.9 TB/s -> ~20 us floor.
//
// R5/R8 plateau: 27.7 us (4.85 TB/s) regardless of per-thread work ->
// latency/occupancy-limited, not issue-limited. Suspect: inlined f64 exp()
// on the cold path inflates VGPR past 64 -> <=4-5 waves/SIMD -> not enough
// outstanding stores.
//
// R9: cold path needs only the DECISION: exp(td) >= 0.1  <=>  td >= ln(0.1)
// in f64 (disagreement window ~2 ulp_f64, hit prob ~1e-8 over 33.5M elems).
// Kept value reuses fast-path f32 m (err ~1e-4 << 2e-2 bf16 tolerance).
// No exp call -> ~8 f64 ops, tiny register cost. __launch_bounds__(256,8)
// pins 8 waves/EU (VGPR <= 64).
//
// Store mapping unchanged from R5/R8: each store instr = wave-contiguous
// 1 KiB (R7 lesson: per-INSTRUCTION contiguity is what matters).

#define LOG2E    1.4426950408889634f
#define LOG2_CUT -3.321928094887362f     // log2(0.1), f32
#define BAND2    2e-3f
#define LN01_D   -2.302585092994045684   // ln(0.1), rounds to nearest double

#if __has_builtin(__builtin_amdgcn_exp2f)
#define FAST_EXP2(x) __builtin_amdgcn_exp2f(x)
#else
#define FAST_EXP2(x) exp2f(x)
#endif

__global__ __launch_bounds__(256, 8) void fuzzyfier_kernel(
    const float* __restrict__ x,     // B*V*S
    const float* __restrict__ fs,    // V*P*2 interleaved (c, sigma)
    float* __restrict__ out,         // B*V*S*P
    int totalPair)                   // (B*V*S*P)/8 row-pair chunks
{
    int idx    = blockIdx.x * 256 + threadIdx.x;
    int stride = gridDim.x * 256;    // 524288 -> (v,q) invariant per thread

    int q4 = (idx & 15) << 2;                    // p base (invariant)
    int j0 = idx >> 4;
    int rA0 = ((j0 >> 2) << 3) + (j0 & 3);
    int v   = (rA0 >> 10) & 7;                   // invariant across stride
    int pb  = (v << 6) + q4;

    float c[4], w[4], sg[4];
    #pragma unroll
    for (int k = 0; k < 4; ++k) {
        float2 cs = reinterpret_cast<const float2*>(fs)[pb + k];  // 4 KB, hot
        c[k]  = cs.x;
        sg[k] = cs.y;
        w[k]  = -LOG2E / (2.0f * (cs.y * cs.y));   // one-time precise div
    }

    float4* o4 = reinterpret_cast<float4*>(out);

    for (int i = idx; i < totalPair; i += stride) {
        int jj   = i >> 4;
        int q    = i & 15;
        int rowA = ((jj >> 2) << 3) + (jj & 3);
        int rowB = rowA + 4;                 // same v (8-row block, 8 | 1024)
        float xa = x[rowA];                  // 16 lanes share -> L1 broadcast
        float xb = x[rowB];

        float oa[4], ob[4];
        #pragma unroll
        for (int k = 0; k < 4; ++k) {
            float da = xa - c[k];
            float ua = (da * da) * w[k];         // = log2(mv)
            float ma = FAST_EXP2(ua);
            oa[k] = (ma >= 0.1f) ? ma : 0.0f;
            if (__builtin_expect(fabsf(ua - LOG2_CUT) < BAND2, 0)) {
                // decision-only f64 replay of numpy's argument chain
                double dd = (double)xa - (double)c[k];
                double sd = (double)sg[k];
                double td = -(dd * dd) / (2.0 * (sd * sd));
                oa[k] = (td >= LN01_D) ? ma : 0.0f;
            }
            float db = xb - c[k];
            float ub = (db * db) * w[k];
            float mb = FAST_EXP2(ub);
            ob[k] = (mb >= 0.1f) ? mb : 0.0f;
            if (__builtin_expect(fabsf(ub - LOG2_CUT) < BAND2, 0)) {
                double dd = (double)xb - (double)c[k];
                double sd = (double)sg[k];
                double td = -(dd * dd) / (2.0 * (sd * sd));
                ob[k] = (td >= LN01_D) ? mb : 0.0f;
            }
        }

        // Each store instruction: wave writes 1 KiB contiguous.
        o4[rowA * 16 + q] = make_float4(oa[0], oa[1], oa[2], oa[3]);
        o4[rowB * 16 + q] = make_float4(ob[0], ob[1], ob[2], ob[3]);
    }
}

extern "C" void kernel_launch(void* const* d_in, const int* in_sizes, int n_in,
                              void* d_out, int out_size, void* d_ws, size_t ws_size,
                              hipStream_t stream) {
    const float* x  = (const float*)d_in[0];
    const float* fs = (const float*)d_in[1];
    float* out      = (float*)d_out;

    int totalPair = out_size / 8;   // 4,194,304 (exactly 8 iters/thread)

    const int block = 256;
    const int grid  = 2048;         // keep ==0 mod 512 for (v,q) invariance

    hipLaunchKernelGGL(fuzzyfier_kernel, dim3(grid), dim3(block), 0, stream,
                       x, fs, out, totalPair);
}